// Round 7
// baseline (231.824 us; speedup 1.0000x reference)
//
#include <hip/hip_runtime.h>
#include <hip/hip_bf16.h>

typedef __hip_bfloat16 bf16;
typedef __attribute__((ext_vector_type(8))) short v8s;   // 8 bf16 (MFMA A/B frag, 16B)
typedef __attribute__((ext_vector_type(4))) float v4f;   // MFMA C/D frag

__device__ __forceinline__ short f2s(float v){ bf16 h = __float2bfloat16(v); return *(short*)&h; }
__device__ __forceinline__ float s2f(short s){ bf16 h = *(bf16*)&s; return __bfloat162float(h); }
__device__ __forceinline__ unsigned pack2(float a, float b){
  return (unsigned)(unsigned short)f2s(a) | ((unsigned)(unsigned short)f2s(b) << 16);
}
__device__ __forceinline__ int SWZ(int row, int idx){ return idx ^ ((row & 7) << 3); }

#define NTOK 1024

// packed-weight arena offsets (shorts): Wp[kg][M][8] with kg = k/8
enum : int {
  PW_ABC = 0,        // [32][384][8] rows: 0-127 Wa1, 128-255 Wgb, 256-383 Wgc
  PW_A2  = 98304,    // [16][128][8]
  PW_B1  = 114688,   // [16][128][8]
  PW_B2  = 131072,   // [16][128][8]
  PW_C1  = 147456,   // [8][128][8]
  PW_C2  = 155648,   // [16][128][8]
  PW_R1  = 172032,   // [48][256][8]
  PW_R2  = 270336,   // [32][256][8]
  PW_END = 335872
};

struct WSegs {
  const float* src[10];
  int dstb[10], Mseg[10], Mtot[10], moff[10], K[10], blk0[10];
};

// ======== phase0: packed tokenize + packed weight convert ========
// ranges: [0,256) tok_c  [256,384) tok_b  [384,640) va pack  [640,804) weights
__global__ __launch_bounds__(256) void phase0_k(WSegs S, short* __restrict__ wb,
                                                const float* __restrict__ va,
                                                const float* __restrict__ vb,
                                                const float* __restrict__ vc,
                                                short* __restrict__ vap,
                                                short* __restrict__ Tbp,
                                                short* __restrict__ Tcp) {
  __shared__ __align__(16) short L[32768];   // 64KB staging
  const int t = threadIdx.x;
  const int bid = blockIdx.x;
  if (bid < 256) {            // vert_c (8b x 8kg x 4hh): planes 128x128, R=4
    int b = bid >> 5, kg = (bid >> 2) & 7, hh = bid & 3;
    const float4* src = (const float4*)vc;
    for (int i = 0; i < 32; ++i) {
      int it = t + i * 256;                       // 8192 float4: [8j][32y][32xq]
      int j = it >> 10, y = (it >> 5) & 31, xq = it & 31;
      float4 v = src[(((long)(b * 64 + kg * 8 + j) * 128) + hh * 32 + y) * 32 + xq];
      short* Lp = &L[(j * 32 + y) * 128 + xq * 4];
      Lp[0] = f2s(v.x); Lp[1] = f2s(v.y); Lp[2] = f2s(v.z); Lp[3] = f2s(v.w);
    }
    __syncthreads();
    for (int i = 0; i < 16; ++i) {
      int ot = t + i * 256;                       // 4096: [16p][8hl][32wn]
      int p = ot >> 8, hl = (ot >> 5) & 7, wn = ot & 31;
      int dy = p >> 2, dx = p & 3;
      v8s pk;
#pragma unroll
      for (int j = 0; j < 8; ++j) pk[j] = L[(j * 32 + hl * 4 + dy) * 128 + wn * 4 + dx];
      int z = b * 16 + p, n = (hh * 8 + hl) * 32 + wn;
      *(v8s*)&Tcp[(((long)z * 8 + kg) * 1024 + n) * 8] = pk;
    }
  } else if (bid < 384) {     // vert_b (8b x 16kg): planes 64x64, R=2
    int i0 = bid - 256;
    int b = i0 >> 4, kg = i0 & 15;
    const float4* src = (const float4*)vb;
    for (int i = 0; i < 32; ++i) {
      int it = t + i * 256;                       // 8192 f4: [8j][64y][16xq]
      int j = it >> 10, y = (it >> 4) & 63, xq = it & 15;
      float4 v = src[(((long)(b * 128 + kg * 8 + j) * 64) + y) * 16 + xq];
      short* Lp = &L[(j * 64 + y) * 64 + xq * 4];
      Lp[0] = f2s(v.x); Lp[1] = f2s(v.y); Lp[2] = f2s(v.z); Lp[3] = f2s(v.w);
    }
    __syncthreads();
    for (int i = 0; i < 16; ++i) {
      int ot = t + i * 256;                       // 4096: [4p][1024n]
      int p = ot >> 10, n = ot & 1023;
      int hn = n >> 5, wn = n & 31, dy = p >> 1, dx = p & 1;
      v8s pk;
#pragma unroll
      for (int j = 0; j < 8; ++j) pk[j] = L[(j * 64 + hn * 2 + dy) * 64 + wn * 2 + dx];
      int z = b * 4 + p;
      *(v8s*)&Tbp[(((long)z * 16 + kg) * 1024 + n) * 8] = pk;
    }
  } else if (bid < 640) {     // vert_a pack (8z x 32kg)
    int i0 = bid - 384;
    int z = i0 >> 5, kg = i0 & 31;
#pragma unroll
    for (int i = 0; i < 4; ++i) {
      int n = t + i * 256;
      v8s pk;
#pragma unroll
      for (int j = 0; j < 8; ++j) pk[j] = f2s(va[((long)(z * 256 + kg * 8 + j)) * 1024 + n]);
      *(v8s*)&vap[(((long)z * 32 + kg) * 1024 + n) * 8] = pk;
    }
  } else {                    // weight pack
    int wblk = bid - 640;
    int s = 0;
    for (int q = 1; q < 10; ++q) if (wblk >= S.blk0[q]) s = q;
    int tt = (wblk - S.blk0[s]) * 256 + t;
    int M = S.Mseg[s], K = S.K[s];
    if (tt < M * (K >> 3)) {
      int m = tt % M, kg = tt / M;
      const float* sp = S.src[s] + (long)m * K + kg * 8;
      v8s pk;
#pragma unroll
      for (int j = 0; j < 8; ++j) pk[j] = f2s(sp[j]);
      *(v8s*)&wb[S.dstb[s] + ((kg * S.Mtot[s] + S.moff[s] + m) << 3)] = pk;
    }
  }
}

// ======== phase1 device: token MLP, A/B direct-from-global, Ht in LDS ========
template<int KG1>
__device__ __forceinline__ void mlp2_dev(char* smem, const short* __restrict__ w1p,
                                         const short* __restrict__ w2p,
                                         const short* __restrict__ Tp,
                                         const float* __restrict__ wvec,
                                         short* __restrict__ E,
                                         float* __restrict__ SB,
                                         int nx, int z) {
  short* Ht = (short*)smem;               // [128n][128h] 32KB; reused as Et [128o][128n]
  float* scl = (float*)(smem + 32768);
  float* wl  = (float*)(smem + 33280);
  const int t = threadIdx.x;
  const int n0 = nx * 128;
  const int l = t & 63, w = t >> 6;
  const int wr = w >> 1, wc = w & 1;
  const int lr = l & 15, lg = l >> 4, ro = lg * 4, lk = lg * 8;
  if (t < 128) { wl[t] = wvec[t]; scl[t] = 0.f; }
  v4f acc[4][4];
#pragma unroll
  for (int mi = 0; mi < 4; ++mi)
#pragma unroll
    for (int ni = 0; ni < 4; ++ni) acc[mi][ni] = (v4f){0.f, 0.f, 0.f, 0.f};
  // layer1: A,B direct global
#pragma unroll
  for (int ks = 0; ks < KG1 / 4; ++ks) {
    v8s af[4], bfv[4];
#pragma unroll
    for (int mi = 0; mi < 4; ++mi)
      af[mi] = *(const v8s*)&w1p[(((ks * 4 + lg) * 128) + wr * 64 + mi * 16 + lr) << 3];
#pragma unroll
    for (int ni = 0; ni < 4; ++ni)
      bfv[ni] = *(const v8s*)&Tp[((((long)z * KG1 + ks * 4 + lg) * 1024) + n0 + wc * 64 + ni * 16 + lr) << 3];
#pragma unroll
    for (int mi = 0; mi < 4; ++mi)
#pragma unroll
      for (int ni = 0; ni < 4; ++ni)
        acc[mi][ni] = __builtin_amdgcn_mfma_f32_16x16x32_bf16(af[mi], bfv[ni], acc[mi][ni], 0, 0, 0);
  }
  // hidden -> Ht (relu, transposed, swizzled)
#pragma unroll
  for (int mi = 0; mi < 4; ++mi)
#pragma unroll
    for (int ni = 0; ni < 4; ++ni) {
      int o = wr * 64 + mi * 16 + ro, nn = wc * 64 + ni * 16 + lr;
#pragma unroll
      for (int rp = 0; rp < 4; rp += 2)
        *(unsigned*)&Ht[nn * 128 + SWZ(nn, o + rp)] =
            pack2(fmaxf(acc[mi][ni][rp], 0.f), fmaxf(acc[mi][ni][rp + 1], 0.f));
    }
  __syncthreads();
  // layer2: A direct global, B from Ht
#pragma unroll
  for (int mi = 0; mi < 4; ++mi)
#pragma unroll
    for (int ni = 0; ni < 4; ++ni) acc[mi][ni] = (v4f){0.f, 0.f, 0.f, 0.f};
#pragma unroll
  for (int ks = 0; ks < 4; ++ks) {
    v8s af[4], bfv[4];
#pragma unroll
    for (int mi = 0; mi < 4; ++mi)
      af[mi] = *(const v8s*)&w2p[(((ks * 4 + lg) * 128) + wr * 64 + mi * 16 + lr) << 3];
#pragma unroll
    for (int ni = 0; ni < 4; ++ni) {
      int nn = wc * 64 + ni * 16 + lr;
      bfv[ni] = *(const v8s*)&Ht[nn * 128 + SWZ(nn, ks * 32 + lk)];
    }
#pragma unroll
    for (int mi = 0; mi < 4; ++mi)
#pragma unroll
      for (int ni = 0; ni < 4; ++ni)
        acc[mi][ni] = __builtin_amdgcn_mfma_f32_16x16x32_bf16(af[mi], bfv[ni], acc[mi][ni], 0, 0, 0);
  }
  // score partials
#pragma unroll
  for (int ni = 0; ni < 4; ++ni) {
    int nn = wc * 64 + ni * 16 + lr;
    float pb = 0.f;
#pragma unroll
    for (int mi = 0; mi < 4; ++mi)
#pragma unroll
      for (int r = 0; r < 4; ++r) pb = fmaf(wl[wr * 64 + mi * 16 + ro + r], acc[mi][ni][r], pb);
    atomicAdd(&scl[nn], pb);
  }
  __syncthreads();   // Ht reads + scl adds complete
  short* Et = Ht;    // [128o][128n]
#pragma unroll
  for (int mi = 0; mi < 4; ++mi)
#pragma unroll
    for (int ni = 0; ni < 4; ++ni)
#pragma unroll
      for (int r = 0; r < 4; ++r) {
        int o = wr * 64 + mi * 16 + ro + r, nn = wc * 64 + ni * 16 + lr;
        Et[o * 128 + SWZ(o, nn)] = f2s(acc[mi][ni][r]);
      }
  __syncthreads();
#pragma unroll
  for (int it = 0; it < 8; ++it) {
    int chunk = it * 256 + t;
    int o = chunk >> 4, n8 = (chunk & 15) * 8;
    v8s pk = *(const v8s*)&Et[o * 128 + SWZ(o, n8)];
    *(v8s*)&E[((long)z * 128 + o) * NTOK + n0 + n8] = pk;
  }
  if (t < 128) SB[(long)z * NTOK + n0 + t] = scl[t];
}

// ======== phase1 device: a-path, A/B direct-from-global ========
__device__ __forceinline__ void mlp_a_dev(char* smem, const short* __restrict__ wb,
                                          const short* __restrict__ vap,
                                          const float* __restrict__ wab,
                                          const float* __restrict__ wac,
                                          short* __restrict__ emb_a,
                                          short* __restrict__ gate_b,
                                          short* __restrict__ gate_c,
                                          float* __restrict__ sa_b,
                                          float* __restrict__ sa_c,
                                          int nx, int z) {
  short* Ht = (short*)smem;               // [64n][128h] 16KB
  short* Gt = (short*)(smem + 16384);     // [128o][64n] 16KB (gates / Et)
  float* sbl = (float*)(smem + 32768);
  float* scl = (float*)(smem + 33024);
  float* wl  = (float*)(smem + 33280);
  float* wcl = (float*)(smem + 33792);
  const int t = threadIdx.x;
  const int n0 = nx * 64;
  const int l = t & 63, w = t >> 6;
  const int lr = l & 15, lg = l >> 4, ro = lg * 4, lk = lg * 8;
  if (t < 128) { wl[t] = wab[t]; wcl[t] = wac[t]; }
  if (t < 64) { sbl[t] = 0.f; scl[t] = 0.f; }
  v4f acc[2][4];
  for (int p = 0; p < 3; ++p) {      // 0: hidden, 1: gate_b, 2: gate_c
#pragma unroll
    for (int mi = 0; mi < 2; ++mi)
#pragma unroll
      for (int ni = 0; ni < 4; ++ni) acc[mi][ni] = (v4f){0.f, 0.f, 0.f, 0.f};
#pragma unroll
    for (int ks = 0; ks < 8; ++ks) {
      v8s af[2], bfv[4];
#pragma unroll
      for (int mi = 0; mi < 2; ++mi)
        af[mi] = *(const v8s*)&wb[PW_ABC + ((((ks * 4 + lg) * 384) + p * 128 + w * 32 + mi * 16 + lr) << 3)];
#pragma unroll
      for (int ni = 0; ni < 4; ++ni)
        bfv[ni] = *(const v8s*)&vap[((((long)z * 32 + ks * 4 + lg) * 1024) + n0 + ni * 16 + lr) << 3];
#pragma unroll
      for (int mi = 0; mi < 2; ++mi)
#pragma unroll
        for (int ni = 0; ni < 4; ++ni)
          acc[mi][ni] = __builtin_amdgcn_mfma_f32_16x16x32_bf16(af[mi], bfv[ni], acc[mi][ni], 0, 0, 0);
    }
    if (p == 0) {
#pragma unroll
      for (int mi = 0; mi < 2; ++mi)
#pragma unroll
        for (int ni = 0; ni < 4; ++ni) {
          int o = w * 32 + mi * 16 + ro, nn = ni * 16 + lr;
#pragma unroll
          for (int rp = 0; rp < 4; rp += 2)
            *(unsigned*)&Ht[nn * 128 + SWZ(nn, o + rp)] =
                pack2(fmaxf(acc[mi][ni][rp], 0.f), fmaxf(acc[mi][ni][rp + 1], 0.f));
        }
    } else {
      short* g = (p == 1) ? gate_b : gate_c;
#pragma unroll
      for (int mi = 0; mi < 2; ++mi)
#pragma unroll
        for (int ni = 0; ni < 4; ++ni)
#pragma unroll
          for (int r = 0; r < 4; ++r) {
            int o = w * 32 + mi * 16 + ro + r, nn = ni * 16 + lr;
            Gt[o * 64 + SWZ(o, nn)] = f2s(1.f / (1.f + __expf(acc[mi][ni][r])));
          }
      __syncthreads();
#pragma unroll
      for (int i = 0; i < 4; ++i) {
        int ot = t + i * 256;                 // 1024 = 128o x 8 v8s
        int o = ot >> 3, n8 = (ot & 7) * 8;
        v8s pk = *(const v8s*)&Gt[o * 64 + SWZ(o, n8)];
        *(v8s*)&g[((long)z * 128 + o) * NTOK + n0 + n8] = pk;
      }
      __syncthreads();
    }
  }
  // layer2: emb_a = Wa2 @ hidden
#pragma unroll
  for (int mi = 0; mi < 2; ++mi)
#pragma unroll
    for (int ni = 0; ni < 4; ++ni) acc[mi][ni] = (v4f){0.f, 0.f, 0.f, 0.f};
#pragma unroll
  for (int ks = 0; ks < 4; ++ks) {
    v8s af[2], bfv[4];
#pragma unroll
    for (int mi = 0; mi < 2; ++mi)
      af[mi] = *(const v8s*)&wb[PW_A2 + ((((ks * 4 + lg) * 128) + w * 32 + mi * 16 + lr) << 3)];
#pragma unroll
    for (int ni = 0; ni < 4; ++ni) {
      int nn = ni * 16 + lr;
      bfv[ni] = *(const v8s*)&Ht[nn * 128 + SWZ(nn, ks * 32 + lk)];
    }
#pragma unroll
    for (int mi = 0; mi < 2; ++mi)
#pragma unroll
      for (int ni = 0; ni < 4; ++ni)
        acc[mi][ni] = __builtin_amdgcn_mfma_f32_16x16x32_bf16(af[mi], bfv[ni], acc[mi][ni], 0, 0, 0);
  }
#pragma unroll
  for (int ni = 0; ni < 4; ++ni) {
    int nn = ni * 16 + lr;
    float pb = 0.f, pc = 0.f;
#pragma unroll
    for (int mi = 0; mi < 2; ++mi)
#pragma unroll
      for (int r = 0; r < 4; ++r) {
        int o = w * 32 + mi * 16 + ro + r;
        float v = acc[mi][ni][r];
        pb = fmaf(wl[o], v, pb);
        pc = fmaf(wcl[o], v, pc);
        Gt[o * 64 + SWZ(o, nn)] = f2s(v);    // Et reuse of Gt
      }
    atomicAdd(&sbl[nn], pb);
    atomicAdd(&scl[nn], pc);
  }
  __syncthreads();
#pragma unroll
  for (int i = 0; i < 4; ++i) {
    int ot = t + i * 256;
    int o = ot >> 3, n8 = (ot & 7) * 8;
    v8s pk = *(const v8s*)&Gt[o * 64 + SWZ(o, n8)];
    *(v8s*)&emb_a[((long)z * 128 + o) * NTOK + n0 + n8] = pk;
  }
  if (t < 64) {
    sa_b[(long)z * NTOK + n0 + t] = sbl[t];
    sa_c[(long)z * NTOK + n0 + t] = scl[t];
  }
}

// ======== phase1: c [0,1024) + b [1024,1280) + a [1280,1408) ========
__global__ __launch_bounds__(256) void phase1_k(const short* __restrict__ wb,
                                                const short* __restrict__ vap,
                                                const short* __restrict__ Tbp,
                                                const short* __restrict__ Tcp,
                                                const float* __restrict__ wab,
                                                const float* __restrict__ wac,
                                                short* emb_a, short* gate_b, short* gate_c,
                                                short* emb_b, short* emb_c,
                                                float* sa_b, float* sa_c,
                                                float* sb_b, float* sb_c) {
  __shared__ __align__(16) char smem[34816];
  int bid = blockIdx.x;
  if (bid < 1024) {
    mlp2_dev<8>(smem, wb + PW_C1, wb + PW_C2, Tcp, wac + 128, emb_c, sb_c, bid & 7, bid >> 3);
  } else if (bid < 1280) {
    int i = bid - 1024;
    mlp2_dev<16>(smem, wb + PW_B1, wb + PW_B2, Tbp, wab + 128, emb_b, sb_b, i & 7, i >> 3);
  } else {
    int i = bid - 1280;
    mlp_a_dev(smem, wb, vap, wab, wac, emb_a, gate_b, gate_c, sa_b, sa_c, i & 15, i >> 4);
  }
}

// ======== attn precompute: softmax over p of relu(sa+sb) ========
__global__ __launch_bounds__(256) void attn_k(const float* __restrict__ sa_b,
                                              const float* __restrict__ sb_b,
                                              const float* __restrict__ sa_c,
                                              const float* __restrict__ sb_c,
                                              float* __restrict__ attn_b,
                                              float* __restrict__ attn_c) {
  int i = blockIdx.x * 256 + threadIdx.x;  // 8192 = b*1024+n
  int b = i >> 10, n = i & 1023;
  {
    float sa = sa_b[i], m = 0.f, s[4], den = 0.f;
#pragma unroll
    for (int p = 0; p < 4; ++p) { s[p] = fmaxf(sa + sb_b[((long)b * 4 + p) * NTOK + n], 0.f); m = fmaxf(m, s[p]); }
#pragma unroll
    for (int p = 0; p < 4; ++p) { s[p] = __expf(s[p] - m); den += s[p]; }
    float r = 1.f / den;
#pragma unroll
    for (int p = 0; p < 4; ++p) attn_b[((long)b * 4 + p) * NTOK + n] = s[p] * r;
  }
  {
    float sa = sa_c[i], m = 0.f, s[16], den = 0.f;
#pragma unroll
    for (int p = 0; p < 16; ++p) { s[p] = fmaxf(sa + sb_c[((long)b * 16 + p) * NTOK + n], 0.f); m = fmaxf(m, s[p]); }
#pragma unroll
    for (int p = 0; p < 16; ++p) { s[p] = __expf(s[p] - m); den += s[p]; }
    float r = 1.f / den;
#pragma unroll
    for (int p = 0; p < 16; ++p) attn_c[((long)b * 16 + p) * NTOK + n] = s[p] * r;
  }
}

// ======== feat: sigmoid([agg_b*gate_b ; agg_c*gate_c ; emb_a]) -> PACKED featp ========
// grid (48 cg, 8 b). thread: c = cg*8 + (t>>5), n-range (t&31)*32.
__global__ __launch_bounds__(256) void feat4_k(const short* __restrict__ emb_b,
                                               const short* __restrict__ emb_c,
                                               const short* __restrict__ emb_a,
                                               const short* __restrict__ gate_b,
                                               const short* __restrict__ gate_c,
                                               const float* __restrict__ attn_b,
                                               const float* __restrict__ attn_c,
                                               short* __restrict__ featp) {
  __shared__ __align__(16) short F[8 * 1024];
  const int t = threadIdx.x;
  const int cg = blockIdx.x, b = blockIdx.y;
  const int cpart = t >> 5, c = cg * 8 + cpart;
  const int nbase = (t & 31) * 32;
  for (int q = 0; q < 4; ++q) {
    int n8 = nbase + q * 8;
    float acc[8];
    if (c < 256) {
#pragma unroll
      for (int j = 0; j < 8; ++j) acc[j] = 0.f;
      if (c < 128) {
#pragma unroll
        for (int p = 0; p < 4; ++p) {
          v8s e = *(const v8s*)&emb_b[(((long)(b * 4 + p)) * 128 + c) * NTOK + n8];
          const float* ap = attn_b + ((long)(b * 4 + p)) * NTOK + n8;
          float4 a0 = *(const float4*)ap, a1 = *(const float4*)(ap + 4);
          acc[0] = fmaf(s2f(e[0]), a0.x, acc[0]); acc[1] = fmaf(s2f(e[1]), a0.y, acc[1]);
          acc[2] = fmaf(s2f(e[2]), a0.z, acc[2]); acc[3] = fmaf(s2f(e[3]), a0.w, acc[3]);
          acc[4] = fmaf(s2f(e[4]), a1.x, acc[4]); acc[5] = fmaf(s2f(e[5]), a1.y, acc[5]);
          acc[6] = fmaf(s2f(e[6]), a1.z, acc[6]); acc[7] = fmaf(s2f(e[7]), a1.w, acc[7]);
        }
        v8s g = *(const v8s*)&gate_b[((long)(b * 128 + c)) * NTOK + n8];
#pragma unroll
        for (int j = 0; j < 8; ++j) acc[j] *= s2f(g[j]);
      } else {
        int cc = c - 128;
#pragma unroll
        for (int p = 0; p < 16; ++p) {
          v8s e = *(const v8s*)&emb_c[(((long)(b * 16 + p)) * 128 + cc) * NTOK + n8];
          const float* ap = attn_c + ((long)(b * 16 + p)) * NTOK + n8;
          float4 a0 = *(const float4*)ap, a1 = *(const float4*)(ap + 4);
          acc[0] = fmaf(s2f(e[0]), a0.x, acc[0]); acc[1] = fmaf(s2f(e[1]), a0.y, acc[1]);
          acc[2] = fmaf(s2f(e[2]), a0.z, acc[2]); acc[3] = fmaf(s2f(e[3]), a0.w, acc[3]);
          acc[4] = fmaf(s2f(e[4]), a1.x, acc[4]); acc[5] = fmaf(s2f(e[5]), a1.y, acc[5]);
          acc[6] = fmaf(s2f(e[6]), a1.z, acc[6]); acc[7] = fmaf(s2f(e[7]), a1.w, acc[7]);
        }
        v8s g = *(const v8s*)&gate_c[((long)(b * 128 + cc)) * NTOK + n8];
#pragma unroll
        for (int j = 0; j < 8; ++j) acc[j] *= s2f(g[j]);
      }
    } else {
      v8s e = *(const v8s*)&emb_a[((long)(b * 128 + (c - 256))) * NTOK + n8];
#pragma unroll
      for (int j = 0; j < 8; ++j) acc[j] = s2f(e[j]);
    }
    v8s o;
#pragma unroll
    for (int j = 0; j < 8; ++j) o[j] = f2s(1.f / (1.f + __expf(-acc[j])));
    *(v8s*)&F[cpart * 1024 + n8] = o;
  }
  __syncthreads();
#pragma unroll
  for (int i = 0; i < 4; ++i) {
    int n = t * 4 + i;
    v8s pk;
#pragma unroll
    for (int j = 0; j < 8; ++j) pk[j] = F[j * 1024 + n];
    *(v8s*)&featp[(((long)b * 48 + cg) * 1024 + n) * 8] = pk;
  }
}

// ======== readout: out = Wr2 @ relu(Wr1 @ featp), A/B direct-global ========
__global__ __launch_bounds__(256) void r12_k(const short* __restrict__ wb,
                                             const short* __restrict__ featp,
                                             float* __restrict__ out) {
  __shared__ __align__(16) char smem[36864];
  short* Ht = (short*)smem;      // [32n][256h] 16KB
  float* Ot = (float*)smem;      // [256o][36n] 36KB (reuse)
  const int t = threadIdx.x;
  const int n0 = blockIdx.x * 32;
  const int z = blockIdx.y;
  const int l = t & 63, w = t >> 6;
  const int lr = l & 15, lg = l >> 4, ro = lg * 4, lk = lg * 8;
  v4f acc[4][2];
#pragma unroll
  for (int mi = 0; mi < 4; ++mi)
#pragma unroll
    for (int ni = 0; ni < 2; ++ni) acc[mi][ni] = (v4f){0.f, 0.f, 0.f, 0.f};
#pragma unroll
  for (int ks = 0; ks < 12; ++ks) {
    v8s af[4], bfv[2];
#pragma unroll
    for (int mi = 0; mi < 4; ++mi)
      af[mi] = *(const v8s*)&wb[PW_R1 + ((((ks * 4 + lg) * 256) + w * 64 + mi * 16 + lr) << 3)];
#pragma unroll
    for (int ni = 0; ni < 2; ++ni)
      bfv[ni] = *(const v8s*)&featp[((((long)z * 48 + ks * 4 + lg) * 1024) + n0 + ni * 16 + lr) << 3];
#pragma unroll
    for (int mi = 0; mi < 4; ++mi)
#pragma unroll
      for (int ni = 0; ni < 2; ++ni)
        acc[mi][ni] = __builtin_amdgcn_mfma_f32_16x16x32_bf16(af[mi], bfv[ni], acc[mi][ni], 0, 0, 0);
  }
#pragma unroll
  for (int mi = 0; mi < 4; ++mi)
#pragma unroll
    for (int ni = 0; ni < 2; ++ni) {
      int o = w * 64 + mi * 16 + ro, nn = ni * 16 + lr;
#pragma unroll
      for (int rp = 0; rp < 4; rp += 2)
        *(unsigned*)&Ht[nn * 256 + SWZ(nn, o + rp)] =
            pack2(fmaxf(acc[mi][ni][rp], 0.f), fmaxf(acc[mi][ni][rp + 1], 0.f));
    }
  __syncthreads();
#pragma unroll
  for (int mi = 0; mi < 4; ++mi)
#pragma unroll
    for (int ni = 0; ni < 2; ++ni) acc[mi][ni] = (v4f){0.f, 0.f, 0.f, 0.f};
#pragma unroll
  for (int ks = 0; ks < 8; ++ks) {
    v8s af[4], bfv[2];
#pragma unroll
    for (int mi = 0; mi < 4; ++mi)
      af[mi] = *(const v8s*)&wb[PW_R2 + ((((ks * 4 + lg) * 256) + w * 64 + mi * 16 + lr) << 3)];
#pragma unroll
    for (int ni = 0; ni < 2; ++ni) {
      int nn = ni * 16 + lr;
      bfv[ni] = *(const v8s*)&Ht[nn * 256 + SWZ(nn, ks * 32 + lk)];
    }
#pragma unroll
    for (int mi = 0; mi < 4; ++mi)
#pragma unroll
      for (int ni = 0; ni < 2; ++ni)
        acc[mi][ni] = __builtin_amdgcn_mfma_f32_16x16x32_bf16(af[mi], bfv[ni], acc[mi][ni], 0, 0, 0);
  }
  __syncthreads();   // Ht dead; reuse as Ot
#pragma unroll
  for (int mi = 0; mi < 4; ++mi)
#pragma unroll
    for (int ni = 0; ni < 2; ++ni)
#pragma unroll
      for (int r = 0; r < 4; ++r) {
        int o = w * 64 + mi * 16 + ro + r, nn = ni * 16 + lr;
        Ot[o * 36 + nn] = acc[mi][ni][r];
      }
  __syncthreads();
#pragma unroll
  for (int it = 0; it < 8; ++it) {
    int chunk = it * 256 + t;
    int o = chunk >> 3, n4 = (chunk & 7) * 4;
    float4 v = *(const float4*)&Ot[o * 36 + n4];
    *(float4*)&out[((long)z * 256 + o) * NTOK + n0 + n4] = v;
  }
}

extern "C" void kernel_launch(void* const* d_in, const int* in_sizes, int n_in,
                              void* d_out, int out_size, void* d_ws, size_t ws_size,
                              hipStream_t stream) {
  const float* vert_a = (const float*)d_in[0];
  const float* vert_b = (const float*)d_in[1];
  const float* vert_c = (const float*)d_in[2];
  const float* wab = (const float*)d_in[11];
  const float* wac = (const float*)d_in[12];

  char* wsb = (char*)d_ws;
  size_t off = 0;
  auto alloc = [&](size_t bytes) { char* p = wsb + off; off += (bytes + 255) & ~(size_t)255; return p; };
  short* wb     = (short*)alloc((size_t)PW_END * 2);
  float* sa_b   = (float*)alloc(8192 * 4);
  float* sa_c   = (float*)alloc(8192 * 4);
  float* sb_b   = (float*)alloc(32768 * 4);
  float* sb_c   = (float*)alloc(131072 * 4);
  float* attn_b = (float*)alloc(32768 * 4);
  float* attn_c = (float*)alloc(131072 * 4);
  short* emb_a  = (short*)alloc((size_t)8 * 128 * 1024 * 2);
  short* gate_b = (short*)alloc((size_t)8 * 128 * 1024 * 2);
  short* gate_c = (short*)alloc((size_t)8 * 128 * 1024 * 2);
  short* emb_b  = (short*)alloc((size_t)32 * 128 * 1024 * 2);
  short* emb_c  = (short*)alloc((size_t)128 * 128 * 1024 * 2);
  short* featp  = (short*)alloc((size_t)8 * 48 * 1024 * 8 * 2);   // 6 MB packed
  short* vap    = (short*)alloc((size_t)8 * 32 * 1024 * 8 * 2);   // 4 MB packed
  short* Tbp    = (short*)alloc((size_t)32 * 16 * 1024 * 8 * 2);  // 8 MB packed
  short* Tcp    = (short*)alloc((size_t)128 * 8 * 1024 * 8 * 2);  // 16 MB packed

  WSegs S;
  const float* srcs[10] = {(const float*)d_in[3], (const float*)d_in[5], (const float*)d_in[6],
                           (const float*)d_in[4], (const float*)d_in[7], (const float*)d_in[8],
                           (const float*)d_in[9], (const float*)d_in[10],
                           (const float*)d_in[13], (const float*)d_in[14]};
  const int dstb[10] = {PW_ABC, PW_ABC, PW_ABC, PW_A2, PW_B1, PW_B2, PW_C1, PW_C2, PW_R1, PW_R2};
  const int Mseg[10] = {128, 128, 128, 128, 128, 128, 128, 128, 256, 256};
  const int Mtot[10] = {384, 384, 384, 128, 128, 128, 128, 128, 256, 256};
  const int moff[10] = {0, 128, 256, 0, 0, 0, 0, 0, 0, 0};
  const int Kk[10]   = {256, 256, 256, 128, 128, 128, 64, 128, 384, 256};
  const int blk0[10] = {0, 16, 32, 48, 56, 64, 72, 76, 84, 132};
  for (int i = 0; i < 10; ++i) {
    S.src[i] = srcs[i]; S.dstb[i] = dstb[i]; S.Mseg[i] = Mseg[i];
    S.Mtot[i] = Mtot[i]; S.moff[i] = moff[i]; S.K[i] = Kk[i]; S.blk0[i] = blk0[i];
  }

  dim3 blk(256);
  phase0_k<<<804, blk, 0, stream>>>(S, wb, vert_a, vert_b, vert_c, vap, Tbp, Tcp);
  phase1_k<<<1408, blk, 0, stream>>>(wb, vap, Tbp, Tcp, wab, wac,
                                     emb_a, gate_b, gate_c, emb_b, emb_c,
                                     sa_b, sa_c, sb_b, sb_c);
  attn_k<<<32, blk, 0, stream>>>(sa_b, sb_b, sa_c, sb_c, attn_b, attn_c);
  feat4_k<<<dim3(48, 8), blk, 0, stream>>>(emb_b, emb_c, emb_a, gate_b, gate_c,
                                           attn_b, attn_c, featp);
  r12_k<<<dim3(32, 8), blk, 0, stream>>>(wb, featp, (float*)d_out);
}

// Round 8
// 207.219 us; speedup vs baseline: 1.1187x; 1.1187x over previous
//
#include <hip/hip_runtime.h>
#include <hip/hip_bf16.h>

typedef __hip_bfloat16 bf16;
typedef __attribute__((ext_vector_type(8))) short v8s;   // 8 bf16 (MFMA A/B frag, 16B)
typedef __attribute__((ext_vector_type(4))) float v4f;   // MFMA C/D frag

__device__ __forceinline__ short f2s(float v){ bf16 h = __float2bfloat16(v); return *(short*)&h; }
__device__ __forceinline__ float s2f(short s){ bf16 h = *(bf16*)&s; return __bfloat162float(h); }
__device__ __forceinline__ unsigned pack2(float a, float b){
  return (unsigned)(unsigned short)f2s(a) | ((unsigned)(unsigned short)f2s(b) << 16);
}

#define NTOK 1024

// packed-weight arena offsets (shorts): Wp[kg][M][8] with kg = k/8
enum : int {
  PW_ABC = 0,        // [32][384][8] rows: 0-127 Wa1, 128-255 Wgb, 256-383 Wgc
  PW_A2  = 98304,    // [16][128][8]
  PW_B1  = 114688,   // [16][128][8]
  PW_B2  = 131072,   // [16][128][8]
  PW_C1  = 147456,   // [8][128][8]
  PW_C2  = 155648,   // [16][128][8]
  PW_R1  = 172032,   // [48][256][8]
  PW_R2  = 270336,   // [32][256][8]
  PW_END = 335872
};

struct WSegs {
  const float* src[10];
  int dstb[10], Mseg[10], Mtot[10], moff[10], K[10], blk0[10];
};

// ======== phase0: packed tokenize + packed weight convert (unchanged r7) ========
__global__ __launch_bounds__(256) void phase0_k(WSegs S, short* __restrict__ wb,
                                                const float* __restrict__ va,
                                                const float* __restrict__ vb,
                                                const float* __restrict__ vc,
                                                short* __restrict__ vap,
                                                short* __restrict__ Tbp,
                                                short* __restrict__ Tcp) {
  __shared__ __align__(16) short L[32768];
  const int t = threadIdx.x;
  const int bid = blockIdx.x;
  if (bid < 256) {            // vert_c (8b x 8kg x 4hh): planes 128x128, R=4
    int b = bid >> 5, kg = (bid >> 2) & 7, hh = bid & 3;
    const float4* src = (const float4*)vc;
    for (int i = 0; i < 32; ++i) {
      int it = t + i * 256;
      int j = it >> 10, y = (it >> 5) & 31, xq = it & 31;
      float4 v = src[(((long)(b * 64 + kg * 8 + j) * 128) + hh * 32 + y) * 32 + xq];
      short* Lp = &L[(j * 32 + y) * 128 + xq * 4];
      Lp[0] = f2s(v.x); Lp[1] = f2s(v.y); Lp[2] = f2s(v.z); Lp[3] = f2s(v.w);
    }
    __syncthreads();
    for (int i = 0; i < 16; ++i) {
      int ot = t + i * 256;
      int p = ot >> 8, hl = (ot >> 5) & 7, wn = ot & 31;
      int dy = p >> 2, dx = p & 3;
      v8s pk;
#pragma unroll
      for (int j = 0; j < 8; ++j) pk[j] = L[(j * 32 + hl * 4 + dy) * 128 + wn * 4 + dx];
      int z = b * 16 + p, n = (hh * 8 + hl) * 32 + wn;
      *(v8s*)&Tcp[(((long)z * 8 + kg) * 1024 + n) * 8] = pk;
    }
  } else if (bid < 384) {     // vert_b (8b x 16kg): planes 64x64, R=2
    int i0 = bid - 256;
    int b = i0 >> 4, kg = i0 & 15;
    const float4* src = (const float4*)vb;
    for (int i = 0; i < 32; ++i) {
      int it = t + i * 256;
      int j = it >> 10, y = (it >> 4) & 63, xq = it & 15;
      float4 v = src[(((long)(b * 128 + kg * 8 + j) * 64) + y) * 16 + xq];
      short* Lp = &L[(j * 64 + y) * 64 + xq * 4];
      Lp[0] = f2s(v.x); Lp[1] = f2s(v.y); Lp[2] = f2s(v.z); Lp[3] = f2s(v.w);
    }
    __syncthreads();
    for (int i = 0; i < 16; ++i) {
      int ot = t + i * 256;
      int p = ot >> 10, n = ot & 1023;
      int hn = n >> 5, wn = n & 31, dy = p >> 1, dx = p & 1;
      v8s pk;
#pragma unroll
      for (int j = 0; j < 8; ++j) pk[j] = L[(j * 64 + hn * 2 + dy) * 64 + wn * 2 + dx];
      int z = b * 4 + p;
      *(v8s*)&Tbp[(((long)z * 16 + kg) * 1024 + n) * 8] = pk;
    }
  } else if (bid < 640) {     // vert_a pack (8z x 32kg)
    int i0 = bid - 384;
    int z = i0 >> 5, kg = i0 & 31;
#pragma unroll
    for (int i = 0; i < 4; ++i) {
      int n = t + i * 256;
      v8s pk;
#pragma unroll
      for (int j = 0; j < 8; ++j) pk[j] = f2s(va[((long)(z * 256 + kg * 8 + j)) * 1024 + n]);
      *(v8s*)&vap[(((long)z * 32 + kg) * 1024 + n) * 8] = pk;
    }
  } else {                    // weight pack
    int wblk = bid - 640;
    int s = 0;
    for (int q = 1; q < 10; ++q) if (wblk >= S.blk0[q]) s = q;
    int tt = (wblk - S.blk0[s]) * 256 + t;
    int M = S.Mseg[s], K = S.K[s];
    if (tt < M * (K >> 3)) {
      int m = tt % M, kg = tt / M;
      const float* sp = S.src[s] + (long)m * K + kg * 8;
      v8s pk;
#pragma unroll
      for (int j = 0; j < 8; ++j) pk[j] = f2s(sp[j]);
      *(v8s*)&wb[S.dstb[s] + ((kg * S.Mtot[s] + S.moff[s] + m) << 3)] = pk;
    }
  }
}

// ======== phase1 device: token MLP — Bs LDS-staged (swizzled), weights direct-L2 ========
// smem: [0,16K) Bs [8kg][128n][8] xor(ns^kg); [16K,48K) Ht [128n][128h] xor(h8^(n&7)) / Et
template<int NSTEP>   // K/64: c=1, b=2
__device__ __forceinline__ void mlp2_dev(char* smem, const short* __restrict__ w1p,
                                         const short* __restrict__ w2p,
                                         const short* __restrict__ Tp,
                                         const float* __restrict__ wvec,
                                         short* __restrict__ E,
                                         float* __restrict__ SB,
                                         int nx, int z) {
  short* Bs = (short*)smem;
  short* Ht = (short*)(smem + 16384);
  float* scl = (float*)(smem + 49152);
  float* wl  = (float*)(smem + 49664);
  const int t = threadIdx.x;
  const int n0 = nx * 128;
  const int l = t & 63, w = t >> 6;
  const int wr = w >> 1, wc = w & 1;
  const int lr = l & 15, lg = l >> 4, ro = lg * 4;
  if (t < 128) { wl[t] = wvec[t]; scl[t] = 0.f; }
  v4f acc[4][4];
#pragma unroll
  for (int mi = 0; mi < 4; ++mi)
#pragma unroll
    for (int ni = 0; ni < 4; ++ni) acc[mi][ni] = (v4f){0.f, 0.f, 0.f, 0.f};
  // ---- layer1, K-steps of 64 ----
  for (int s = 0; s < NSTEP; ++s) {
    if (s) __syncthreads();
#pragma unroll
    for (int i = 0; i < 4; ++i) {        // stage 16KB: 4 chunks/thread
      int idx = t + i * 256;
      int kg = idx >> 7, ns = idx & 127;
      int gn = n0 + (ns ^ kg);           // pre-swizzled source
      v8s pk = *(const v8s*)&Tp[(((long)z * (NSTEP * 8) + s * 8 + kg) * 1024 + gn) << 3];
      *(v8s*)&Bs[(kg * 128 + ns) << 3] = pk;
    }
    __syncthreads();
#pragma unroll
    for (int ks = 0; ks < 2; ++ks) {
      v8s af[4], bfv[4];
      int kg = ks * 4 + lg;
#pragma unroll
      for (int mi = 0; mi < 4; ++mi)
        af[mi] = *(const v8s*)&w1p[(((s * 8 + kg) * 128) + wr * 64 + mi * 16 + lr) << 3];
#pragma unroll
      for (int ni = 0; ni < 4; ++ni) {
        int nn = wc * 64 + ni * 16 + lr;
        bfv[ni] = *(const v8s*)&Bs[((kg * 128) + (nn ^ kg)) << 3];
      }
#pragma unroll
      for (int mi = 0; mi < 4; ++mi)
#pragma unroll
        for (int ni = 0; ni < 4; ++ni)
          acc[mi][ni] = __builtin_amdgcn_mfma_f32_16x16x32_bf16(af[mi], bfv[ni], acc[mi][ni], 0, 0, 0);
    }
  }
  // ---- hidden -> Ht (relu, transposed, h8-swizzled) ----
#pragma unroll
  for (int mi = 0; mi < 4; ++mi)
#pragma unroll
    for (int ni = 0; ni < 4; ++ni) {
      int nn = wc * 64 + ni * 16 + lr;
#pragma unroll
      for (int rp = 0; rp < 4; rp += 2) {
        int h = wr * 64 + mi * 16 + ro + rp;
        *(unsigned*)&Ht[nn * 128 + (((h >> 3) ^ (nn & 7)) << 3) + (h & 7)] =
            pack2(fmaxf(acc[mi][ni][rp], 0.f), fmaxf(acc[mi][ni][rp + 1], 0.f));
      }
    }
  __syncthreads();
  // ---- layer2 (K=128), A=W2 direct-L2, B from Ht ----
#pragma unroll
  for (int mi = 0; mi < 4; ++mi)
#pragma unroll
    for (int ni = 0; ni < 4; ++ni) acc[mi][ni] = (v4f){0.f, 0.f, 0.f, 0.f};
#pragma unroll 2
  for (int ks2 = 0; ks2 < 4; ++ks2) {
    v8s af[4], bfv[4];
    int kg2 = ks2 * 4 + lg;
#pragma unroll
    for (int mi = 0; mi < 4; ++mi)
      af[mi] = *(const v8s*)&w2p[((kg2 * 128) + wr * 64 + mi * 16 + lr) << 3];
#pragma unroll
    for (int ni = 0; ni < 4; ++ni) {
      int nn = wc * 64 + ni * 16 + lr;
      bfv[ni] = *(const v8s*)&Ht[nn * 128 + ((kg2 ^ (nn & 7)) << 3)];
    }
#pragma unroll
    for (int mi = 0; mi < 4; ++mi)
#pragma unroll
      for (int ni = 0; ni < 4; ++ni)
        acc[mi][ni] = __builtin_amdgcn_mfma_f32_16x16x32_bf16(af[mi], bfv[ni], acc[mi][ni], 0, 0, 0);
  }
  // ---- score partials ----
#pragma unroll
  for (int ni = 0; ni < 4; ++ni) {
    int nn = wc * 64 + ni * 16 + lr;
    float pb = 0.f;
#pragma unroll
    for (int mi = 0; mi < 4; ++mi)
#pragma unroll
      for (int r = 0; r < 4; ++r) pb = fmaf(wl[wr * 64 + mi * 16 + ro + r], acc[mi][ni][r], pb);
    atomicAdd(&scl[nn], pb);
  }
  __syncthreads();   // Ht reads + scl complete
  short* Et = Ht;    // [128o][128n]
#pragma unroll
  for (int mi = 0; mi < 4; ++mi)
#pragma unroll
    for (int ni = 0; ni < 4; ++ni)
#pragma unroll
      for (int r = 0; r < 4; ++r) {
        int o = wr * 64 + mi * 16 + ro + r, nn = wc * 64 + ni * 16 + lr;
        Et[o * 128 + nn] = f2s(acc[mi][ni][r]);
      }
  __syncthreads();
#pragma unroll
  for (int i = 0; i < 8; ++i) {
    int idx = i * 256 + t;
    int o = idx >> 4, n8 = (idx & 15) * 8;
    v8s pk = *(const v8s*)&Et[o * 128 + n8];
    *(v8s*)&E[((long)z * 128 + o) * NTOK + n0 + n8] = pk;
  }
  if (t < 128) SB[(long)z * NTOK + n0 + t] = scl[t];
}

// ======== phase1 device: a-path — va K=256 fully staged (32KB), 3 M-passes ========
// smem: [0,16K) Ht/Gt/Et; [16K,48K) BsA [32kg][64n][8] xor(ns^(kg&7))
__device__ __forceinline__ void mlp_a_dev(char* smem, const short* __restrict__ wb,
                                          const short* __restrict__ vap,
                                          const float* __restrict__ wab,
                                          const float* __restrict__ wac,
                                          short* __restrict__ emb_a,
                                          short* __restrict__ gate_b,
                                          short* __restrict__ gate_c,
                                          float* __restrict__ sa_b,
                                          float* __restrict__ sa_c,
                                          int nx, int z) {
  short* HG = (short*)smem;               // 16KB: Ht [64n][128h] / Gt,Et [128o][64n]
  short* Bs = (short*)(smem + 16384);     // 32KB
  float* sbl = (float*)(smem + 49152);
  float* scl = (float*)(smem + 49408);
  float* wl  = (float*)(smem + 49664);
  float* wcl = (float*)(smem + 50176);
  const int t = threadIdx.x;
  const int n0 = nx * 64;
  const int l = t & 63, w = t >> 6;
  const int lr = l & 15, lg = l >> 4, ro = lg * 4;
  const int wr2 = w >> 1, wc2 = w & 1;
  if (t < 128) { wl[t] = wab[t]; wcl[t] = wac[t]; }
  if (t < 64) { sbl[t] = 0.f; scl[t] = 0.f; }
#pragma unroll
  for (int i = 0; i < 8; ++i) {          // stage 32KB: 8 chunks/thread
    int idx = t + i * 256;
    int kg = idx >> 6, ns = idx & 63;
    int gn = n0 + (ns ^ (kg & 7));
    v8s pk = *(const v8s*)&vap[(((long)z * 32 + kg) * 1024 + gn) << 3];
    *(v8s*)&Bs[(kg * 64 + ns) << 3] = pk;
  }
  __syncthreads();
  v4f acc[2][4];
  auto l1pass = [&](int p) {
#pragma unroll
    for (int mi = 0; mi < 2; ++mi)
#pragma unroll
      for (int ni = 0; ni < 4; ++ni) acc[mi][ni] = (v4f){0.f, 0.f, 0.f, 0.f};
#pragma unroll 2
    for (int ks = 0; ks < 8; ++ks) {
      v8s af[2], bfv[4];
      int kg = ks * 4 + lg;
#pragma unroll
      for (int mi = 0; mi < 2; ++mi)
        af[mi] = *(const v8s*)&wb[PW_ABC + ((kg * 384 + p * 128 + w * 32 + mi * 16 + lr) << 3)];
#pragma unroll
      for (int ni = 0; ni < 4; ++ni) {
        int nn = ni * 16 + lr;
        bfv[ni] = *(const v8s*)&Bs[((kg * 64) + (nn ^ (kg & 7))) << 3];
      }
#pragma unroll
      for (int mi = 0; mi < 2; ++mi)
#pragma unroll
        for (int ni = 0; ni < 4; ++ni)
          acc[mi][ni] = __builtin_amdgcn_mfma_f32_16x16x32_bf16(af[mi], bfv[ni], acc[mi][ni], 0, 0, 0);
    }
  };
  // ---- p0: hidden -> Ht [64n][128h] swizzled ----
  l1pass(0);
#pragma unroll
  for (int mi = 0; mi < 2; ++mi)
#pragma unroll
    for (int ni = 0; ni < 4; ++ni) {
      int nn = ni * 16 + lr;
#pragma unroll
      for (int rp = 0; rp < 4; rp += 2) {
        int h = w * 32 + mi * 16 + ro + rp;
        *(unsigned*)&HG[nn * 128 + (((h >> 3) ^ (nn & 7)) << 3) + (h & 7)] =
            pack2(fmaxf(acc[mi][ni][rp], 0.f), fmaxf(acc[mi][ni][rp + 1], 0.f));
      }
    }
  __syncthreads();
  // ---- layer2: emb_a (M=128, N=64), waves 2x2 ----
  v4f acc2[4][2];
#pragma unroll
  for (int mi = 0; mi < 4; ++mi)
#pragma unroll
    for (int ni = 0; ni < 2; ++ni) acc2[mi][ni] = (v4f){0.f, 0.f, 0.f, 0.f};
#pragma unroll 2
  for (int ks2 = 0; ks2 < 4; ++ks2) {
    v8s af[4], bfv[2];
    int kg2 = ks2 * 4 + lg;
#pragma unroll
    for (int mi = 0; mi < 4; ++mi)
      af[mi] = *(const v8s*)&wb[PW_A2 + ((kg2 * 128 + wr2 * 64 + mi * 16 + lr) << 3)];
#pragma unroll
    for (int ni = 0; ni < 2; ++ni) {
      int nn = wc2 * 32 + ni * 16 + lr;
      bfv[ni] = *(const v8s*)&HG[nn * 128 + ((kg2 ^ (nn & 7)) << 3)];
    }
#pragma unroll
    for (int mi = 0; mi < 4; ++mi)
#pragma unroll
      for (int ni = 0; ni < 2; ++ni)
        acc2[mi][ni] = __builtin_amdgcn_mfma_f32_16x16x32_bf16(af[mi], bfv[ni], acc2[mi][ni], 0, 0, 0);
  }
#pragma unroll
  for (int ni = 0; ni < 2; ++ni) {
    int nn = wc2 * 32 + ni * 16 + lr;
    float pb = 0.f, pc = 0.f;
#pragma unroll
    for (int mi = 0; mi < 4; ++mi)
#pragma unroll
      for (int r = 0; r < 4; ++r) {
        int o = wr2 * 64 + mi * 16 + ro + r;
        pb = fmaf(wl[o], acc2[mi][ni][r], pb);
        pc = fmaf(wcl[o], acc2[mi][ni][r], pc);
      }
    atomicAdd(&sbl[nn], pb);
    atomicAdd(&scl[nn], pc);
  }
  __syncthreads();   // Ht reads + atomics done
#pragma unroll
  for (int mi = 0; mi < 4; ++mi)
#pragma unroll
    for (int ni = 0; ni < 2; ++ni)
#pragma unroll
      for (int r = 0; r < 4; ++r) {
        int o = wr2 * 64 + mi * 16 + ro + r, nn = wc2 * 32 + ni * 16 + lr;
        HG[o * 64 + nn] = f2s(acc2[mi][ni][r]);   // Et [128o][64n]
      }
  __syncthreads();
#pragma unroll
  for (int i = 0; i < 4; ++i) {
    int idx = i * 256 + t;
    int o = idx >> 3, n8 = (idx & 7) * 8;
    v8s pk = *(const v8s*)&HG[o * 64 + n8];
    *(v8s*)&emb_a[((long)z * 128 + o) * NTOK + n0 + n8] = pk;
  }
  if (t < 64) {
    sa_b[(long)z * NTOK + n0 + t] = sbl[t];
    sa_c[(long)z * NTOK + n0 + t] = scl[t];
  }
  __syncthreads();   // Et reads done before Gt reuse
  // ---- p1/p2: gates ----
  for (int p = 1; p < 3; ++p) {
    l1pass(p);
#pragma unroll
    for (int mi = 0; mi < 2; ++mi)
#pragma unroll
      for (int ni = 0; ni < 4; ++ni)
#pragma unroll
        for (int r = 0; r < 4; ++r) {
          int o = w * 32 + mi * 16 + ro + r, nn = ni * 16 + lr;
          HG[o * 64 + nn] = f2s(1.f / (1.f + __expf(acc[mi][ni][r])));
        }
    __syncthreads();
    short* g = (p == 1) ? gate_b : gate_c;
#pragma unroll
    for (int i = 0; i < 4; ++i) {
      int idx = i * 256 + t;
      int o = idx >> 3, n8 = (idx & 7) * 8;
      v8s pk = *(const v8s*)&HG[o * 64 + n8];
      *(v8s*)&g[((long)z * 128 + o) * NTOK + n0 + n8] = pk;
    }
    __syncthreads();
  }
}

// ======== phase1: a [0,128) + b [128,384) + c [384,1408) — heavy first ========
__global__ __launch_bounds__(256) void phase1_k(const short* __restrict__ wb,
                                                const short* __restrict__ vap,
                                                const short* __restrict__ Tbp,
                                                const short* __restrict__ Tcp,
                                                const float* __restrict__ wab,
                                                const float* __restrict__ wac,
                                                short* emb_a, short* gate_b, short* gate_c,
                                                short* emb_b, short* emb_c,
                                                float* sa_b, float* sa_c,
                                                float* sb_b, float* sb_c) {
  __shared__ __align__(16) char smem[50944];
  int bid = blockIdx.x;
  if (bid < 128) {
    mlp_a_dev(smem, wb, vap, wab, wac, emb_a, gate_b, gate_c, sa_b, sa_c, bid & 15, bid >> 4);
  } else if (bid < 384) {
    int i = bid - 128;
    mlp2_dev<2>(smem, wb + PW_B1, wb + PW_B2, Tbp, wab + 128, emb_b, sb_b, i & 7, i >> 3);
  } else {
    int i = bid - 384;
    mlp2_dev<1>(smem, wb + PW_C1, wb + PW_C2, Tcp, wac + 128, emb_c, sb_c, i & 7, i >> 3);
  }
}

// ======== attn precompute (unchanged) ========
__global__ __launch_bounds__(256) void attn_k(const float* __restrict__ sa_b,
                                              const float* __restrict__ sb_b,
                                              const float* __restrict__ sa_c,
                                              const float* __restrict__ sb_c,
                                              float* __restrict__ attn_b,
                                              float* __restrict__ attn_c) {
  int i = blockIdx.x * 256 + threadIdx.x;
  int b = i >> 10, n = i & 1023;
  {
    float sa = sa_b[i], m = 0.f, s[4], den = 0.f;
#pragma unroll
    for (int p = 0; p < 4; ++p) { s[p] = fmaxf(sa + sb_b[((long)b * 4 + p) * NTOK + n], 0.f); m = fmaxf(m, s[p]); }
#pragma unroll
    for (int p = 0; p < 4; ++p) { s[p] = __expf(s[p] - m); den += s[p]; }
    float r = 1.f / den;
#pragma unroll
    for (int p = 0; p < 4; ++p) attn_b[((long)b * 4 + p) * NTOK + n] = s[p] * r;
  }
  {
    float sa = sa_c[i], m = 0.f, s[16], den = 0.f;
#pragma unroll
    for (int p = 0; p < 16; ++p) { s[p] = fmaxf(sa + sb_c[((long)b * 16 + p) * NTOK + n], 0.f); m = fmaxf(m, s[p]); }
#pragma unroll
    for (int p = 0; p < 16; ++p) { s[p] = __expf(s[p] - m); den += s[p]; }
    float r = 1.f / den;
#pragma unroll
    for (int p = 0; p < 16; ++p) attn_c[((long)b * 16 + p) * NTOK + n] = s[p] * r;
  }
}

// ======== feat -> packed featp (unchanged r7) ========
__global__ __launch_bounds__(256) void feat4_k(const short* __restrict__ emb_b,
                                               const short* __restrict__ emb_c,
                                               const short* __restrict__ emb_a,
                                               const short* __restrict__ gate_b,
                                               const short* __restrict__ gate_c,
                                               const float* __restrict__ attn_b,
                                               const float* __restrict__ attn_c,
                                               short* __restrict__ featp) {
  __shared__ __align__(16) short F[8 * 1024];
  const int t = threadIdx.x;
  const int cg = blockIdx.x, b = blockIdx.y;
  const int cpart = t >> 5, c = cg * 8 + cpart;
  const int nbase = (t & 31) * 32;
  for (int q = 0; q < 4; ++q) {
    int n8 = nbase + q * 8;
    float acc[8];
    if (c < 256) {
#pragma unroll
      for (int j = 0; j < 8; ++j) acc[j] = 0.f;
      if (c < 128) {
#pragma unroll
        for (int p = 0; p < 4; ++p) {
          v8s e = *(const v8s*)&emb_b[(((long)(b * 4 + p)) * 128 + c) * NTOK + n8];
          const float* ap = attn_b + ((long)(b * 4 + p)) * NTOK + n8;
          float4 a0 = *(const float4*)ap, a1 = *(const float4*)(ap + 4);
          acc[0] = fmaf(s2f(e[0]), a0.x, acc[0]); acc[1] = fmaf(s2f(e[1]), a0.y, acc[1]);
          acc[2] = fmaf(s2f(e[2]), a0.z, acc[2]); acc[3] = fmaf(s2f(e[3]), a0.w, acc[3]);
          acc[4] = fmaf(s2f(e[4]), a1.x, acc[4]); acc[5] = fmaf(s2f(e[5]), a1.y, acc[5]);
          acc[6] = fmaf(s2f(e[6]), a1.z, acc[6]); acc[7] = fmaf(s2f(e[7]), a1.w, acc[7]);
        }
        v8s g = *(const v8s*)&gate_b[((long)(b * 128 + c)) * NTOK + n8];
#pragma unroll
        for (int j = 0; j < 8; ++j) acc[j] *= s2f(g[j]);
      } else {
        int cc = c - 128;
#pragma unroll
        for (int p = 0; p < 16; ++p) {
          v8s e = *(const v8s*)&emb_c[(((long)(b * 16 + p)) * 128 + cc) * NTOK + n8];
          const float* ap = attn_c + ((long)(b * 16 + p)) * NTOK + n8;
          float4 a0 = *(const float4*)ap, a1 = *(const float4*)(ap + 4);
          acc[0] = fmaf(s2f(e[0]), a0.x, acc[0]); acc[1] = fmaf(s2f(e[1]), a0.y, acc[1]);
          acc[2] = fmaf(s2f(e[2]), a0.z, acc[2]); acc[3] = fmaf(s2f(e[3]), a0.w, acc[3]);
          acc[4] = fmaf(s2f(e[4]), a1.x, acc[4]); acc[5] = fmaf(s2f(e[5]), a1.y, acc[5]);
          acc[6] = fmaf(s2f(e[6]), a1.z, acc[6]); acc[7] = fmaf(s2f(e[7]), a1.w, acc[7]);
        }
        v8s g = *(const v8s*)&gate_c[((long)(b * 128 + cc)) * NTOK + n8];
#pragma unroll
        for (int j = 0; j < 8; ++j) acc[j] *= s2f(g[j]);
      }
    } else {
      v8s e = *(const v8s*)&emb_a[((long)(b * 128 + (c - 256))) * NTOK + n8];
#pragma unroll
      for (int j = 0; j < 8; ++j) acc[j] = s2f(e[j]);
    }
    v8s o;
#pragma unroll
    for (int j = 0; j < 8; ++j) o[j] = f2s(1.f / (1.f + __expf(-acc[j])));
    *(v8s*)&F[cpart * 1024 + n8] = o;
  }
  __syncthreads();
#pragma unroll
  for (int i = 0; i < 4; ++i) {
    int n = t * 4 + i;
    v8s pk;
#pragma unroll
    for (int j = 0; j < 8; ++j) pk[j] = F[j * 1024 + n];
    *(v8s*)&featp[(((long)b * 48 + cg) * 1024 + n) * 8] = pk;
  }
}

// ======== readout (unchanged r7) ========
__global__ __launch_bounds__(256) void r12_k(const short* __restrict__ wb,
                                             const short* __restrict__ featp,
                                             float* __restrict__ out) {
  __shared__ __align__(16) char smem[36864];
  short* Ht = (short*)smem;
  float* Ot = (float*)smem;
  const int t = threadIdx.x;
  const int n0 = blockIdx.x * 32;
  const int z = blockIdx.y;
  const int l = t & 63, w = t >> 6;
  const int lr = l & 15, lg = l >> 4, ro = lg * 4, lk = lg * 8;
  v4f acc[4][2];
#pragma unroll
  for (int mi = 0; mi < 4; ++mi)
#pragma unroll
    for (int ni = 0; ni < 2; ++ni) acc[mi][ni] = (v4f){0.f, 0.f, 0.f, 0.f};
#pragma unroll 2
  for (int ks = 0; ks < 12; ++ks) {
    v8s af[4], bfv[2];
#pragma unroll
    for (int mi = 0; mi < 4; ++mi)
      af[mi] = *(const v8s*)&wb[PW_R1 + ((((ks * 4 + lg) * 256) + w * 64 + mi * 16 + lr) << 3)];
#pragma unroll
    for (int ni = 0; ni < 2; ++ni)
      bfv[ni] = *(const v8s*)&featp[((((long)z * 48 + ks * 4 + lg) * 1024) + n0 + ni * 16 + lr) << 3];
#pragma unroll
    for (int mi = 0; mi < 4; ++mi)
#pragma unroll
      for (int ni = 0; ni < 2; ++ni)
        acc[mi][ni] = __builtin_amdgcn_mfma_f32_16x16x32_bf16(af[mi], bfv[ni], acc[mi][ni], 0, 0, 0);
  }
#pragma unroll
  for (int mi = 0; mi < 4; ++mi)
#pragma unroll
    for (int ni = 0; ni < 2; ++ni) {
      int o = w * 64 + mi * 16 + ro, nn = ni * 16 + lr;
#pragma unroll
      for (int rp = 0; rp < 4; rp += 2)
        *(unsigned*)&Ht[nn * 256 + ((o + rp) ^ ((nn & 7) << 3))] =
            pack2(fmaxf(acc[mi][ni][rp], 0.f), fmaxf(acc[mi][ni][rp + 1], 0.f));
    }
  __syncthreads();
#pragma unroll
  for (int mi = 0; mi < 4; ++mi)
#pragma unroll
    for (int ni = 0; ni < 2; ++ni) acc[mi][ni] = (v4f){0.f, 0.f, 0.f, 0.f};
#pragma unroll 2
  for (int ks = 0; ks < 8; ++ks) {
    v8s af[4], bfv[2];
#pragma unroll
    for (int mi = 0; mi < 4; ++mi)
      af[mi] = *(const v8s*)&wb[PW_R2 + ((((ks * 4 + lg) * 256) + w * 64 + mi * 16 + lr) << 3)];
#pragma unroll
    for (int ni = 0; ni < 2; ++ni) {
      int nn = ni * 16 + lr;
      bfv[ni] = *(const v8s*)&Ht[nn * 256 + ((ks * 32 + lk) ^ ((nn & 7) << 3))];
    }
#pragma unroll
    for (int mi = 0; mi < 4; ++mi)
#pragma unroll
      for (int ni = 0; ni < 2; ++ni)
        acc[mi][ni] = __builtin_amdgcn_mfma_f32_16x16x32_bf16(af[mi], bfv[ni], acc[mi][ni], 0, 0, 0);
  }
  __syncthreads();
#pragma unroll
  for (int mi = 0; mi < 4; ++mi)
#pragma unroll
    for (int ni = 0; ni < 2; ++ni)
#pragma unroll
      for (int r = 0; r < 4; ++r) {
        int o = w * 64 + mi * 16 + ro + r, nn = ni * 16 + lr;
        Ot[o * 36 + nn] = acc[mi][ni][r];
      }
  __syncthreads();
#pragma unroll
  for (int it = 0; it < 8; ++it) {
    int chunk = it * 256 + t;
    int o = chunk >> 3, n4 = (chunk & 7) * 4;
    float4 v = *(const float4*)&Ot[o * 36 + n4];
    *(float4*)&out[((long)z * 256 + o) * NTOK + n0 + n4] = v;
  }
}

extern "C" void kernel_launch(void* const* d_in, const int* in_sizes, int n_in,
                              void* d_out, int out_size, void* d_ws, size_t ws_size,
                              hipStream_t stream) {
  const float* vert_a = (const float*)d_in[0];
  const float* vert_b = (const float*)d_in[1];
  const float* vert_c = (const float*)d_in[2];
  const float* wab = (const float*)d_in[11];
  const float* wac = (const float*)d_in[12];

  char* wsb = (char*)d_ws;
  size_t off = 0;
  auto alloc = [&](size_t bytes) { char* p = wsb + off; off += (bytes + 255) & ~(size_t)255; return p; };
  short* wb     = (short*)alloc((size_t)PW_END * 2);
  float* sa_b   = (float*)alloc(8192 * 4);
  float* sa_c   = (float*)alloc(8192 * 4);
  float* sb_b   = (float*)alloc(32768 * 4);
  float* sb_c   = (float*)alloc(131072 * 4);
  float* attn_b = (float*)alloc(32768 * 4);
  float* attn_c = (float*)alloc(131072 * 4);
  short* emb_a  = (short*)alloc((size_t)8 * 128 * 1024 * 2);
  short* gate_b = (short*)alloc((size_t)8 * 128 * 1024 * 2);
  short* gate_c = (short*)alloc((size_t)8 * 128 * 1024 * 2);
  short* emb_b  = (short*)alloc((size_t)32 * 128 * 1024 * 2);
  short* emb_c  = (short*)alloc((size_t)128 * 128 * 1024 * 2);
  short* featp  = (short*)alloc((size_t)8 * 48 * 1024 * 8 * 2);
  short* vap    = (short*)alloc((size_t)8 * 32 * 1024 * 8 * 2);
  short* Tbp    = (short*)alloc((size_t)32 * 16 * 1024 * 8 * 2);
  short* Tcp    = (short*)alloc((size_t)128 * 8 * 1024 * 8 * 2);

  WSegs S;
  const float* srcs[10] = {(const float*)d_in[3], (const float*)d_in[5], (const float*)d_in[6],
                           (const float*)d_in[4], (const float*)d_in[7], (const float*)d_in[8],
                           (const float*)d_in[9], (const float*)d_in[10],
                           (const float*)d_in[13], (const float*)d_in[14]};
  const int dstb[10] = {PW_ABC, PW_ABC, PW_ABC, PW_A2, PW_B1, PW_B2, PW_C1, PW_C2, PW_R1, PW_R2};
  const int Mseg[10] = {128, 128, 128, 128, 128, 128, 128, 128, 256, 256};
  const int Mtot[10] = {384, 384, 384, 128, 128, 128, 128, 128, 256, 256};
  const int moff[10] = {0, 128, 256, 0, 0, 0, 0, 0, 0, 0};
  const int Kk[10]   = {256, 256, 256, 128, 128, 128, 64, 128, 384, 256};
  const int blk0[10] = {0, 16, 32, 48, 56, 64, 72, 76, 84, 132};
  for (int i = 0; i < 10; ++i) {
    S.src[i] = srcs[i]; S.dstb[i] = dstb[i]; S.Mseg[i] = Mseg[i];
    S.Mtot[i] = Mtot[i]; S.moff[i] = moff[i]; S.K[i] = Kk[i]; S.blk0[i] = blk0[i];
  }

  dim3 blk(256);
  phase0_k<<<804, blk, 0, stream>>>(S, wb, vert_a, vert_b, vert_c, vap, Tbp, Tcp);
  phase1_k<<<1408, blk, 0, stream>>>(wb, vap, Tbp, Tcp, wab, wac,
                                     emb_a, gate_b, gate_c, emb_b, emb_c,
                                     sa_b, sa_c, sb_b, sb_c);
  attn_k<<<32, blk, 0, stream>>>(sa_b, sb_b, sa_c, sb_c, attn_b, attn_c);
  feat4_k<<<dim3(48, 8), blk, 0, stream>>>(emb_b, emb_c, emb_a, gate_b, gate_c,
                                           attn_b, attn_c, featp);
  r12_k<<<dim3(32, 8), blk, 0, stream>>>(wb, featp, (float*)d_out);
}

// Round 9
// 190.143 us; speedup vs baseline: 1.2192x; 1.0898x over previous
//
#include <hip/hip_runtime.h>
#include <hip/hip_bf16.h>

typedef __hip_bfloat16 bf16;
typedef __attribute__((ext_vector_type(8))) short v8s;   // 8 bf16 (MFMA A/B frag, 16B)
typedef __attribute__((ext_vector_type(4))) float v4f;   // MFMA C/D frag

__device__ __forceinline__ short f2s(float v){ bf16 h = __float2bfloat16(v); return *(short*)&h; }
__device__ __forceinline__ float s2f(short s){ bf16 h = *(bf16*)&s; return __bfloat162float(h); }
__device__ __forceinline__ unsigned pack2(float a, float b){
  return (unsigned)(unsigned short)f2s(a) | ((unsigned)(unsigned short)f2s(b) << 16);
}

#define NTOK 1024

// packed-weight arena offsets (shorts): Wp[kg][M][8] with kg = k/8
enum : int {
  PW_ABC = 0,        // [32][384][8] rows: 0-127 Wa1, 128-255 Wgb, 256-383 Wgc
  PW_A2  = 98304,    // [16][128][8]
  PW_B1  = 114688,   // [16][128][8]
  PW_B2  = 131072,   // [16][128][8]
  PW_C1  = 147456,   // [8][128][8]
  PW_C2  = 155648,   // [16][128][8]
  PW_R1  = 172032,   // [48][256][8]
  PW_R2  = 270336,   // [32][256][8]
  PW_END = 335872
};

struct WSegs {
  const float* src[10];
  int dstb[10], Mseg[10], Mtot[10], moff[10], K[10], blk0[10];
};

// ======== phase0: packed tokenize + packed weight convert ========
__global__ __launch_bounds__(256) void phase0_k(WSegs S, short* __restrict__ wb,
                                                const float* __restrict__ va,
                                                const float* __restrict__ vb,
                                                const float* __restrict__ vc,
                                                short* __restrict__ vap,
                                                short* __restrict__ Tbp,
                                                short* __restrict__ Tcp) {
  __shared__ __align__(16) short L[32768];
  const int t = threadIdx.x;
  const int bid = blockIdx.x;
  if (bid < 256) {            // vert_c (8b x 8kg x 4hh): planes 128x128, R=4
    int b = bid >> 5, kg = (bid >> 2) & 7, hh = bid & 3;
    const float4* src = (const float4*)vc;
    for (int i = 0; i < 32; ++i) {
      int it = t + i * 256;
      int j = it >> 10, y = (it >> 5) & 31, xq = it & 31;
      float4 v = src[(((long)(b * 64 + kg * 8 + j) * 128) + hh * 32 + y) * 32 + xq];
      short* Lp = &L[(j * 32 + y) * 128 + xq * 4];
      Lp[0] = f2s(v.x); Lp[1] = f2s(v.y); Lp[2] = f2s(v.z); Lp[3] = f2s(v.w);
    }
    __syncthreads();
    for (int i = 0; i < 16; ++i) {
      int ot = t + i * 256;
      int p = ot >> 8, hl = (ot >> 5) & 7, wn = ot & 31;
      int dy = p >> 2, dx = p & 3;
      v8s pk;
#pragma unroll
      for (int j = 0; j < 8; ++j) pk[j] = L[(j * 32 + hl * 4 + dy) * 128 + wn * 4 + dx];
      int z = b * 16 + p, n = (hh * 8 + hl) * 32 + wn;
      *(v8s*)&Tcp[(((long)z * 8 + kg) * 1024 + n) * 8] = pk;
    }
  } else if (bid < 384) {     // vert_b (8b x 16kg): planes 64x64, R=2
    int i0 = bid - 256;
    int b = i0 >> 4, kg = i0 & 15;
    const float4* src = (const float4*)vb;
    for (int i = 0; i < 32; ++i) {
      int it = t + i * 256;
      int j = it >> 10, y = (it >> 4) & 63, xq = it & 15;
      float4 v = src[(((long)(b * 128 + kg * 8 + j) * 64) + y) * 16 + xq];
      short* Lp = &L[(j * 64 + y) * 64 + xq * 4];
      Lp[0] = f2s(v.x); Lp[1] = f2s(v.y); Lp[2] = f2s(v.z); Lp[3] = f2s(v.w);
    }
    __syncthreads();
    for (int i = 0; i < 16; ++i) {
      int ot = t + i * 256;
      int p = ot >> 10, n = ot & 1023;
      int hn = n >> 5, wn = n & 31, dy = p >> 1, dx = p & 1;
      v8s pk;
#pragma unroll
      for (int j = 0; j < 8; ++j) pk[j] = L[(j * 64 + hn * 2 + dy) * 64 + wn * 2 + dx];
      int z = b * 4 + p;
      *(v8s*)&Tbp[(((long)z * 16 + kg) * 1024 + n) * 8] = pk;
    }
  } else if (bid < 640) {     // vert_a pack (8z x 32kg)
    int i0 = bid - 384;
    int z = i0 >> 5, kg = i0 & 31;
#pragma unroll
    for (int i = 0; i < 4; ++i) {
      int n = t + i * 256;
      v8s pk;
#pragma unroll
      for (int j = 0; j < 8; ++j) pk[j] = f2s(va[((long)(z * 256 + kg * 8 + j)) * 1024 + n]);
      *(v8s*)&vap[(((long)z * 32 + kg) * 1024 + n) * 8] = pk;
    }
  } else {                    // weight pack
    int wblk = bid - 640;
    int s = 0;
    for (int q = 1; q < 10; ++q) if (wblk >= S.blk0[q]) s = q;
    int tt = (wblk - S.blk0[s]) * 256 + t;
    int M = S.Mseg[s], K = S.K[s];
    if (tt < M * (K >> 3)) {
      int m = tt % M, kg = tt / M;
      const float* sp = S.src[s] + (long)m * K + kg * 8;
      v8s pk;
#pragma unroll
      for (int j = 0; j < 8; ++j) pk[j] = f2s(sp[j]);
      *(v8s*)&wb[S.dstb[s] + ((kg * S.Mtot[s] + S.moff[s] + m) << 3)] = pk;
    }
  }
}

// ======== phase1 unified block: 2-layer MLP (or layer1-gate), Bs aliased in Ht ========
// smem: [0,32K) Ht [128n][128h] (Bs [8kg][128n][8] aliased in [0,16K) during layer1)
// MODE 0: layer1+layer2 -> E + score(wv1).  MODE 1: + second score(wv2) (a-path main).
// MODE 2: layer1 only, output = 1-sigmoid -> E (gates).
template<int NSTEP, int MS, int MODE>
__device__ __forceinline__ void mlp2u(char* smem, const short* __restrict__ w1p, int moff,
                                      const short* __restrict__ w2p,
                                      const short* __restrict__ Tp,
                                      const float* __restrict__ wv1,
                                      const float* __restrict__ wv2,
                                      short* __restrict__ E,
                                      float* __restrict__ SB1,
                                      float* __restrict__ SB2,
                                      int nx, int z) {
  short* Bs = (short*)smem;
  short* Ht = (short*)smem;
  float* sbl = (float*)(smem + 32768);
  float* scl = (float*)(smem + 33280);
  float* wl  = (float*)(smem + 33792);
  float* wcl = (float*)(smem + 34304);
  const int t = threadIdx.x;
  const int n0 = nx * 128;
  const int l = t & 63, w = t >> 6;
  const int wr = w >> 1, wc = w & 1;
  const int lr = l & 15, lg = l >> 4, ro = lg * 4;
  if (MODE != 2 && t < 128) {
    wl[t] = wv1[t]; sbl[t] = 0.f;
    if (MODE == 1) { wcl[t] = wv2[t]; scl[t] = 0.f; }
  }
  v4f acc[4][4];
#pragma unroll
  for (int mi = 0; mi < 4; ++mi)
#pragma unroll
    for (int ni = 0; ni < 4; ++ni) acc[mi][ni] = (v4f){0.f, 0.f, 0.f, 0.f};
  // ---- layer1 over K, steps of 64 ----
  for (int s = 0; s < NSTEP; ++s) {
    if (s || MODE != 2) __syncthreads();   // writes below overwrite Bs region
#pragma unroll
    for (int i = 0; i < 4; ++i) {          // stage 16KB
      int idx = t + i * 256;
      int kg = idx >> 7, ns = idx & 127;
      int gn = n0 + (ns ^ kg);             // pre-swizzled source
      v8s pk = *(const v8s*)&Tp[(((long)z * (NSTEP * 8) + s * 8 + kg) * 1024 + gn) << 3];
      *(v8s*)&Bs[(kg * 128 + ns) << 3] = pk;
    }
    __syncthreads();
#pragma unroll
    for (int ks = 0; ks < 2; ++ks) {
      v8s af[4], bfv[4];
      int kg = ks * 4 + lg;
#pragma unroll
      for (int mi = 0; mi < 4; ++mi)
        af[mi] = *(const v8s*)&w1p[(((s * 8 + kg) * MS) + moff + wr * 64 + mi * 16 + lr) << 3];
#pragma unroll
      for (int ni = 0; ni < 4; ++ni) {
        int nn = wc * 64 + ni * 16 + lr;
        bfv[ni] = *(const v8s*)&Bs[((kg * 128) + (nn ^ kg)) << 3];
      }
#pragma unroll
      for (int mi = 0; mi < 4; ++mi)
#pragma unroll
        for (int ni = 0; ni < 4; ++ni)
          acc[mi][ni] = __builtin_amdgcn_mfma_f32_16x16x32_bf16(af[mi], bfv[ni], acc[mi][ni], 0, 0, 0);
    }
  }
  __syncthreads();   // all Bs reads done; Ht region free
  if (MODE == 2) {
    // gates: 1-sigmoid -> Et [128o][128n] -> vectorized store
#pragma unroll
    for (int mi = 0; mi < 4; ++mi)
#pragma unroll
      for (int ni = 0; ni < 4; ++ni)
#pragma unroll
        for (int r = 0; r < 4; ++r) {
          int o = wr * 64 + mi * 16 + ro + r, nn = wc * 64 + ni * 16 + lr;
          Ht[o * 128 + nn] = f2s(1.f / (1.f + __expf(acc[mi][ni][r])));
        }
    __syncthreads();
#pragma unroll
    for (int i = 0; i < 8; ++i) {
      int idx = i * 256 + t;
      int o = idx >> 4, n8 = (idx & 15) * 8;
      v8s pk = *(const v8s*)&Ht[o * 128 + n8];
      *(v8s*)&E[((long)z * 128 + o) * NTOK + n0 + n8] = pk;
    }
    return;
  }
  // ---- hidden -> Ht (relu, transposed, h8-swizzled) ----
#pragma unroll
  for (int mi = 0; mi < 4; ++mi)
#pragma unroll
    for (int ni = 0; ni < 4; ++ni) {
      int nn = wc * 64 + ni * 16 + lr;
#pragma unroll
      for (int rp = 0; rp < 4; rp += 2) {
        int h = wr * 64 + mi * 16 + ro + rp;
        *(unsigned*)&Ht[nn * 128 + (((h >> 3) ^ (nn & 7)) << 3) + (h & 7)] =
            pack2(fmaxf(acc[mi][ni][rp], 0.f), fmaxf(acc[mi][ni][rp + 1], 0.f));
      }
    }
  __syncthreads();
  // ---- layer2 (K=128), A=W2 direct-L2, B from Ht ----
#pragma unroll
  for (int mi = 0; mi < 4; ++mi)
#pragma unroll
    for (int ni = 0; ni < 4; ++ni) acc[mi][ni] = (v4f){0.f, 0.f, 0.f, 0.f};
#pragma unroll 2
  for (int ks2 = 0; ks2 < 4; ++ks2) {
    v8s af[4], bfv[4];
    int kg2 = ks2 * 4 + lg;
#pragma unroll
    for (int mi = 0; mi < 4; ++mi)
      af[mi] = *(const v8s*)&w2p[((kg2 * 128) + wr * 64 + mi * 16 + lr) << 3];
#pragma unroll
    for (int ni = 0; ni < 4; ++ni) {
      int nn = wc * 64 + ni * 16 + lr;
      bfv[ni] = *(const v8s*)&Ht[nn * 128 + ((kg2 ^ (nn & 7)) << 3)];
    }
#pragma unroll
    for (int mi = 0; mi < 4; ++mi)
#pragma unroll
      for (int ni = 0; ni < 4; ++ni)
        acc[mi][ni] = __builtin_amdgcn_mfma_f32_16x16x32_bf16(af[mi], bfv[ni], acc[mi][ni], 0, 0, 0);
  }
  // ---- score partials ----
#pragma unroll
  for (int ni = 0; ni < 4; ++ni) {
    int nn = wc * 64 + ni * 16 + lr;
    float pb = 0.f, pc = 0.f;
#pragma unroll
    for (int mi = 0; mi < 4; ++mi)
#pragma unroll
      for (int r = 0; r < 4; ++r) {
        float v = acc[mi][ni][r];
        int o = wr * 64 + mi * 16 + ro + r;
        pb = fmaf(wl[o], v, pb);
        if (MODE == 1) pc = fmaf(wcl[o], v, pc);
      }
    atomicAdd(&sbl[nn], pb);
    if (MODE == 1) atomicAdd(&scl[nn], pc);
  }
  __syncthreads();   // layer2 Ht reads + atomics done
  short* Et = Ht;    // [128o][128n]
#pragma unroll
  for (int mi = 0; mi < 4; ++mi)
#pragma unroll
    for (int ni = 0; ni < 4; ++ni)
#pragma unroll
      for (int r = 0; r < 4; ++r) {
        int o = wr * 64 + mi * 16 + ro + r, nn = wc * 64 + ni * 16 + lr;
        Et[o * 128 + nn] = f2s(acc[mi][ni][r]);
      }
  __syncthreads();
#pragma unroll
  for (int i = 0; i < 8; ++i) {
    int idx = i * 256 + t;
    int o = idx >> 4, n8 = (idx & 15) * 8;
    v8s pk = *(const v8s*)&Et[o * 128 + n8];
    *(v8s*)&E[((long)z * 128 + o) * NTOK + n0 + n8] = pk;
  }
  if (t < 128) {
    SB1[(long)z * NTOK + n0 + t] = sbl[t];
    if (MODE == 1) SB2[(long)z * NTOK + n0 + t] = scl[t];
  }
}

// ======== phase1: c [0,1024) + b [1024,1280) + a-main [1280,1344) + gates [1344,1472) ====
__global__ __launch_bounds__(256, 4) void phase1_k(const short* __restrict__ wb,
                                                   const short* __restrict__ vap,
                                                   const short* __restrict__ Tbp,
                                                   const short* __restrict__ Tcp,
                                                   const float* __restrict__ wab,
                                                   const float* __restrict__ wac,
                                                   short* emb_a, short* gate_b, short* gate_c,
                                                   short* emb_b, short* emb_c,
                                                   float* sa_b, float* sa_c,
                                                   float* sb_b, float* sb_c) {
  __shared__ __align__(16) char smem[34816];
  int bid = blockIdx.x;
  if (bid < 1024) {
    mlp2u<1, 128, 0>(smem, wb + PW_C1, 0, wb + PW_C2, Tcp, wac + 128, nullptr,
                     emb_c, sb_c, nullptr, bid & 7, bid >> 3);
  } else if (bid < 1280) {
    int i = bid - 1024;
    mlp2u<2, 128, 0>(smem, wb + PW_B1, 0, wb + PW_B2, Tbp, wab + 128, nullptr,
                     emb_b, sb_b, nullptr, i & 7, i >> 3);
  } else if (bid < 1344) {
    int i = bid - 1280;
    mlp2u<4, 384, 1>(smem, wb + PW_ABC, 0, wb + PW_A2, vap, wab, wac,
                     emb_a, sa_b, sa_c, i & 7, i >> 3);
  } else {
    int i = bid - 1344;                  // 128 blocks: 2 gates x 8nx x 8z
    int g = i >> 6, j = i & 63;
    mlp2u<4, 384, 2>(smem, wb + PW_ABC, (g + 1) * 128, nullptr, vap, nullptr, nullptr,
                     g ? gate_c : gate_b, nullptr, nullptr, j & 7, j >> 3);
  }
}

// ======== attn precompute ========
__global__ __launch_bounds__(256) void attn_k(const float* __restrict__ sa_b,
                                              const float* __restrict__ sb_b,
                                              const float* __restrict__ sa_c,
                                              const float* __restrict__ sb_c,
                                              float* __restrict__ attn_b,
                                              float* __restrict__ attn_c) {
  int i = blockIdx.x * 256 + threadIdx.x;
  int b = i >> 10, n = i & 1023;
  {
    float sa = sa_b[i], m = 0.f, s[4], den = 0.f;
#pragma unroll
    for (int p = 0; p < 4; ++p) { s[p] = fmaxf(sa + sb_b[((long)b * 4 + p) * NTOK + n], 0.f); m = fmaxf(m, s[p]); }
#pragma unroll
    for (int p = 0; p < 4; ++p) { s[p] = __expf(s[p] - m); den += s[p]; }
    float r = 1.f / den;
#pragma unroll
    for (int p = 0; p < 4; ++p) attn_b[((long)b * 4 + p) * NTOK + n] = s[p] * r;
  }
  {
    float sa = sa_c[i], m = 0.f, s[16], den = 0.f;
#pragma unroll
    for (int p = 0; p < 16; ++p) { s[p] = fmaxf(sa + sb_c[((long)b * 16 + p) * NTOK + n], 0.f); m = fmaxf(m, s[p]); }
#pragma unroll
    for (int p = 0; p < 16; ++p) { s[p] = __expf(s[p] - m); den += s[p]; }
    float r = 1.f / den;
#pragma unroll
    for (int p = 0; p < 16; ++p) attn_c[((long)b * 16 + p) * NTOK + n] = s[p] * r;
  }
}

// ======== feat5: perfectly-coalesced aggregate + packed featp ========
// grid (48,8). thread: ch=t>>7 selects c half; lanes 0-127 cover n contiguously (16B each).
__global__ __launch_bounds__(256) void feat5_k(const short* __restrict__ emb_b,
                                               const short* __restrict__ emb_c,
                                               const short* __restrict__ emb_a,
                                               const short* __restrict__ gate_b,
                                               const short* __restrict__ gate_c,
                                               const float* __restrict__ attn_b,
                                               const float* __restrict__ attn_c,
                                               short* __restrict__ featp) {
  __shared__ __align__(16) short F[8 * 1024];
  const int t = threadIdx.x;
  const int cg = blockIdx.x, b = blockIdx.y;
  const int ch = t >> 7, n8 = (t & 127) * 8;
  for (int cc = 0; cc < 4; ++cc) {
    const int c = cg * 8 + ch * 4 + cc;
    float acc[8];
    if (c < 256) {
#pragma unroll
      for (int j = 0; j < 8; ++j) acc[j] = 0.f;
      if (c < 128) {
#pragma unroll
        for (int p = 0; p < 4; ++p) {
          v8s e = *(const v8s*)&emb_b[(((long)(b * 4 + p)) * 128 + c) * NTOK + n8];
          const float* ap = attn_b + ((long)(b * 4 + p)) * NTOK + n8;
          float4 a0 = *(const float4*)ap, a1 = *(const float4*)(ap + 4);
          acc[0] = fmaf(s2f(e[0]), a0.x, acc[0]); acc[1] = fmaf(s2f(e[1]), a0.y, acc[1]);
          acc[2] = fmaf(s2f(e[2]), a0.z, acc[2]); acc[3] = fmaf(s2f(e[3]), a0.w, acc[3]);
          acc[4] = fmaf(s2f(e[4]), a1.x, acc[4]); acc[5] = fmaf(s2f(e[5]), a1.y, acc[5]);
          acc[6] = fmaf(s2f(e[6]), a1.z, acc[6]); acc[7] = fmaf(s2f(e[7]), a1.w, acc[7]);
        }
        v8s g = *(const v8s*)&gate_b[((long)(b * 128 + c)) * NTOK + n8];
#pragma unroll
        for (int j = 0; j < 8; ++j) acc[j] *= s2f(g[j]);
      } else {
        int cc2 = c - 128;
#pragma unroll
        for (int p = 0; p < 16; ++p) {
          v8s e = *(const v8s*)&emb_c[(((long)(b * 16 + p)) * 128 + cc2) * NTOK + n8];
          const float* ap = attn_c + ((long)(b * 16 + p)) * NTOK + n8;
          float4 a0 = *(const float4*)ap, a1 = *(const float4*)(ap + 4);
          acc[0] = fmaf(s2f(e[0]), a0.x, acc[0]); acc[1] = fmaf(s2f(e[1]), a0.y, acc[1]);
          acc[2] = fmaf(s2f(e[2]), a0.z, acc[2]); acc[3] = fmaf(s2f(e[3]), a0.w, acc[3]);
          acc[4] = fmaf(s2f(e[4]), a1.x, acc[4]); acc[5] = fmaf(s2f(e[5]), a1.y, acc[5]);
          acc[6] = fmaf(s2f(e[6]), a1.z, acc[6]); acc[7] = fmaf(s2f(e[7]), a1.w, acc[7]);
        }
        v8s g = *(const v8s*)&gate_c[((long)(b * 128 + cc2)) * NTOK + n8];
#pragma unroll
        for (int j = 0; j < 8; ++j) acc[j] *= s2f(g[j]);
      }
    } else {
      v8s e = *(const v8s*)&emb_a[((long)(b * 128 + (c - 256))) * NTOK + n8];
#pragma unroll
      for (int j = 0; j < 8; ++j) acc[j] = s2f(e[j]);
    }
    v8s o;
#pragma unroll
    for (int j = 0; j < 8; ++j) o[j] = f2s(1.f / (1.f + __expf(-acc[j])));
    *(v8s*)&F[(ch * 4 + cc) * 1024 + n8] = o;
  }
  __syncthreads();
#pragma unroll
  for (int i = 0; i < 4; ++i) {
    int n = t * 4 + i;
    v8s pk;
#pragma unroll
    for (int j = 0; j < 8; ++j) pk[j] = F[j * 1024 + n];
    *(v8s*)&featp[(((long)b * 48 + cg) * 1024 + n) * 8] = pk;
  }
}

// ======== readout: out = Wr2 @ relu(Wr1 @ featp), A/B direct-global ========
__global__ __launch_bounds__(256) void r12_k(const short* __restrict__ wb,
                                             const short* __restrict__ featp,
                                             float* __restrict__ out) {
  __shared__ __align__(16) char smem[36864];
  short* Ht = (short*)smem;
  float* Ot = (float*)smem;
  const int t = threadIdx.x;
  const int n0 = blockIdx.x * 32;
  const int z = blockIdx.y;
  const int l = t & 63, w = t >> 6;
  const int lr = l & 15, lg = l >> 4, ro = lg * 4, lk = lg * 8;
  v4f acc[4][2];
#pragma unroll
  for (int mi = 0; mi < 4; ++mi)
#pragma unroll
    for (int ni = 0; ni < 2; ++ni) acc[mi][ni] = (v4f){0.f, 0.f, 0.f, 0.f};
#pragma unroll 2
  for (int ks = 0; ks < 12; ++ks) {
    v8s af[4], bfv[2];
#pragma unroll
    for (int mi = 0; mi < 4; ++mi)
      af[mi] = *(const v8s*)&wb[PW_R1 + ((((ks * 4 + lg) * 256) + w * 64 + mi * 16 + lr) << 3)];
#pragma unroll
    for (int ni = 0; ni < 2; ++ni)
      bfv[ni] = *(const v8s*)&featp[((((long)z * 48 + ks * 4 + lg) * 1024) + n0 + ni * 16 + lr) << 3];
#pragma unroll
    for (int mi = 0; mi < 4; ++mi)
#pragma unroll
      for (int ni = 0; ni < 2; ++ni)
        acc[mi][ni] = __builtin_amdgcn_mfma_f32_16x16x32_bf16(af[mi], bfv[ni], acc[mi][ni], 0, 0, 0);
  }
#pragma unroll
  for (int mi = 0; mi < 4; ++mi)
#pragma unroll
    for (int ni = 0; ni < 2; ++ni) {
      int o = w * 64 + mi * 16 + ro, nn = ni * 16 + lr;
#pragma unroll
      for (int rp = 0; rp < 4; rp += 2)
        *(unsigned*)&Ht[nn * 256 + ((o + rp) ^ ((nn & 7) << 3))] =
            pack2(fmaxf(acc[mi][ni][rp], 0.f), fmaxf(acc[mi][ni][rp + 1], 0.f));
    }
  __syncthreads();
#pragma unroll
  for (int mi = 0; mi < 4; ++mi)
#pragma unroll
    for (int ni = 0; ni < 2; ++ni) acc[mi][ni] = (v4f){0.f, 0.f, 0.f, 0.f};
#pragma unroll 2
  for (int ks = 0; ks < 8; ++ks) {
    v8s af[4], bfv[2];
#pragma unroll
    for (int mi = 0; mi < 4; ++mi)
      af[mi] = *(const v8s*)&wb[PW_R2 + ((((ks * 4 + lg) * 256) + w * 64 + mi * 16 + lr) << 3)];
#pragma unroll
    for (int ni = 0; ni < 2; ++ni) {
      int nn = ni * 16 + lr;
      bfv[ni] = *(const v8s*)&Ht[nn * 256 + ((ks * 32 + lk) ^ ((nn & 7) << 3))];
    }
#pragma unroll
    for (int mi = 0; mi < 4; ++mi)
#pragma unroll
      for (int ni = 0; ni < 2; ++ni)
        acc[mi][ni] = __builtin_amdgcn_mfma_f32_16x16x32_bf16(af[mi], bfv[ni], acc[mi][ni], 0, 0, 0);
  }
  __syncthreads();
#pragma unroll
  for (int mi = 0; mi < 4; ++mi)
#pragma unroll
    for (int ni = 0; ni < 2; ++ni)
#pragma unroll
      for (int r = 0; r < 4; ++r) {
        int o = w * 64 + mi * 16 + ro + r, nn = ni * 16 + lr;
        Ot[o * 36 + nn] = acc[mi][ni][r];
      }
  __syncthreads();
#pragma unroll
  for (int it = 0; it < 8; ++it) {
    int chunk = it * 256 + t;
    int o = chunk >> 3, n4 = (chunk & 7) * 4;
    float4 v = *(const float4*)&Ot[o * 36 + n4];
    *(float4*)&out[((long)z * 256 + o) * NTOK + n0 + n4] = v;
  }
}

extern "C" void kernel_launch(void* const* d_in, const int* in_sizes, int n_in,
                              void* d_out, int out_size, void* d_ws, size_t ws_size,
                              hipStream_t stream) {
  const float* vert_a = (const float*)d_in[0];
  const float* vert_b = (const float*)d_in[1];
  const float* vert_c = (const float*)d_in[2];
  const float* wab = (const float*)d_in[11];
  const float* wac = (const float*)d_in[12];

  char* wsb = (char*)d_ws;
  size_t off = 0;
  auto alloc = [&](size_t bytes) { char* p = wsb + off; off += (bytes + 255) & ~(size_t)255; return p; };
  short* wb     = (short*)alloc((size_t)PW_END * 2);
  float* sa_b   = (float*)alloc(8192 * 4);
  float* sa_c   = (float*)alloc(8192 * 4);
  float* sb_b   = (float*)alloc(32768 * 4);
  float* sb_c   = (float*)alloc(131072 * 4);
  float* attn_b = (float*)alloc(32768 * 4);
  float* attn_c = (float*)alloc(131072 * 4);
  short* emb_a  = (short*)alloc((size_t)8 * 128 * 1024 * 2);
  short* gate_b = (short*)alloc((size_t)8 * 128 * 1024 * 2);
  short* gate_c = (short*)alloc((size_t)8 * 128 * 1024 * 2);
  short* emb_b  = (short*)alloc((size_t)32 * 128 * 1024 * 2);
  short* emb_c  = (short*)alloc((size_t)128 * 128 * 1024 * 2);
  short* featp  = (short*)alloc((size_t)8 * 48 * 1024 * 8 * 2);
  short* vap    = (short*)alloc((size_t)8 * 32 * 1024 * 8 * 2);
  short* Tbp    = (short*)alloc((size_t)32 * 16 * 1024 * 8 * 2);
  short* Tcp    = (short*)alloc((size_t)128 * 8 * 1024 * 8 * 2);

  WSegs S;
  const float* srcs[10] = {(const float*)d_in[3], (const float*)d_in[5], (const float*)d_in[6],
                           (const float*)d_in[4], (const float*)d_in[7], (const float*)d_in[8],
                           (const float*)d_in[9], (const float*)d_in[10],
                           (const float*)d_in[13], (const float*)d_in[14]};
  const int dstb[10] = {PW_ABC, PW_ABC, PW_ABC, PW_A2, PW_B1, PW_B2, PW_C1, PW_C2, PW_R1, PW_R2};
  const int Mseg[10] = {128, 128, 128, 128, 128, 128, 128, 128, 256, 256};
  const int Mtot[10] = {384, 384, 384, 128, 128, 128, 128, 128, 256, 256};
  const int moff[10] = {0, 128, 256, 0, 0, 0, 0, 0, 0, 0};
  const int Kk[10]   = {256, 256, 256, 128, 128, 128, 64, 128, 384, 256};
  const int blk0[10] = {0, 16, 32, 48, 56, 64, 72, 76, 84, 132};
  for (int i = 0; i < 10; ++i) {
    S.src[i] = srcs[i]; S.dstb[i] = dstb[i]; S.Mseg[i] = Mseg[i];
    S.Mtot[i] = Mtot[i]; S.moff[i] = moff[i]; S.K[i] = Kk[i]; S.blk0[i] = blk0[i];
  }

  dim3 blk(256);
  phase0_k<<<804, blk, 0, stream>>>(S, wb, vert_a, vert_b, vert_c, vap, Tbp, Tcp);
  phase1_k<<<1472, blk, 0, stream>>>(wb, vap, Tbp, Tcp, wab, wac,
                                     emb_a, gate_b, gate_c, emb_b, emb_c,
                                     sa_b, sa_c, sb_b, sb_c);
  attn_k<<<32, blk, 0, stream>>>(sa_b, sb_b, sa_c, sb_c, attn_b, attn_c);
  feat5_k<<<dim3(48, 8), blk, 0, stream>>>(emb_b, emb_c, emb_a, gate_b, gate_c,
                                           attn_b, attn_c, featp);
  r12_k<<<dim3(32, 8), blk, 0, stream>>>(wb, featp, (float*)d_out);
}